// Round 1
// baseline (25.301 us; speedup 1.0000x reference)
//
#include <hip/hip_runtime.h>

// MultiHeadAttention with TRIPLE softmax along keys.
// Mathematical collapse: softmax(softmax(softmax(scores))) is uniform(1/S)
// to within ~1e-7 elementwise (second softmax flattens probabilities to
// 1/N + p/N, third to 1/N + p/N^2). Therefore
//   out[b,s,:] = ((mean_s' v[b,s',:]) @ Wv.T + bv) @ Wo.T + bo
// independent of q, k, Wq, Wk, padding_mask, and of the query position s.
// Predicted absmax vs reference ~1e-6, threshold 2.34e-3.

#define BATCH 4
#define SEQ 1024
#define DIM 1024
#define RCHUNKS 32          // 32 row-chunks of 32 rows each for the column sum

// ---- Kernel 1: partial column sums of v: part[b][rc][d] = sum over 32 rows ----
__global__ void colsum_partial_kernel(const float* __restrict__ v,
                                      float* __restrict__ part) {
    const int b  = blockIdx.x;
    const int d  = blockIdx.y * 256 + threadIdx.x;   // 0..1023
    const int rc = blockIdx.z;                        // 0..31
    const float* p = v + ((size_t)b * SEQ + (size_t)rc * 32) * DIM + d;
    float s = 0.0f;
#pragma unroll
    for (int i = 0; i < 32; ++i) s += p[(size_t)i * DIM];
    part[((size_t)b * RCHUNKS + rc) * DIM + d] = s;
}

// ---- Kernel 2: finalize mean: vmean[b][d] = (1/SEQ) * sum_rc part[b][rc][d] ----
__global__ void colsum_final_kernel(const float* __restrict__ part,
                                    float* __restrict__ vmean) {
    const int b = blockIdx.x;
    const int d = blockIdx.y * 256 + threadIdx.x;
    float s = 0.0f;
#pragma unroll
    for (int rc = 0; rc < RCHUNKS; ++rc)
        s += part[((size_t)b * RCHUNKS + rc) * DIM + d];
    vmean[(size_t)b * DIM + d] = s * (1.0f / SEQ);
}

// ---- Kernel 3: y[b][n] = sum_k x[b][k] * W[n][k] + bias[n]  (torch Linear) ----
// One 64-lane wave per output element n; float4 loads along k (coalesced).
__global__ void matvec_bt_kernel(const float* __restrict__ x,
                                 const float* __restrict__ W,
                                 const float* __restrict__ bias,
                                 float* __restrict__ y) {
    const int b    = blockIdx.x;
    const int wave = threadIdx.x >> 6;   // 0..3
    const int lane = threadIdx.x & 63;
    const int n    = blockIdx.y * 4 + wave;

    const float4* x4 = (const float4*)(x + (size_t)b * DIM);
    const float4* w4 = (const float4*)(W + (size_t)n * DIM);

    float s = 0.0f;
#pragma unroll
    for (int k = lane; k < DIM / 4; k += 64) {
        float4 a = x4[k];
        float4 w = w4[k];
        s += a.x * w.x + a.y * w.y + a.z * w.z + a.w * w.w;
    }
#pragma unroll
    for (int off = 32; off > 0; off >>= 1) s += __shfl_down(s, off, 64);
    if (lane == 0) y[(size_t)b * DIM + n] = s + bias[n];
}

// ---- Kernel 4: broadcast r[b][:] to out[b][s][:] with float4 stores ----
__global__ void bcast_kernel(const float* __restrict__ r, float4* __restrict__ out) {
    const size_t total = (size_t)BATCH * SEQ * (DIM / 4);   // 1M float4
    const float4* r4 = (const float4*)r;
    for (size_t i = (size_t)blockIdx.x * blockDim.x + threadIdx.x; i < total;
         i += (size_t)gridDim.x * blockDim.x) {
        const size_t n4 = i & (DIM / 4 - 1);      // column (in float4 units)
        const size_t bs = i >> 8;                 // (b*SEQ + s)
        const size_t b  = bs >> 10;               // / SEQ
        out[i] = r4[b * (DIM / 4) + n4];
    }
}

extern "C" void kernel_launch(void* const* d_in, const int* in_sizes, int n_in,
                              void* d_out, int out_size, void* d_ws, size_t ws_size,
                              hipStream_t stream) {
    const float* v  = (const float*)d_in[2];
    const float* Wv = (const float*)d_in[8];
    const float* bv = (const float*)d_in[9];
    const float* Wo = (const float*)d_in[10];
    const float* bo = (const float*)d_in[11];
    float* out = (float*)d_out;

    // Workspace layout (floats):
    float* part  = (float*)d_ws;                       // B*RCHUNKS*DIM = 131072
    float* vmean = part + (size_t)BATCH * RCHUNKS * DIM; // B*DIM = 4096
    float* t     = vmean + (size_t)BATCH * DIM;          // B*DIM
    float* r     = t + (size_t)BATCH * DIM;              // B*DIM

    // 1) column-sum partials of v
    colsum_partial_kernel<<<dim3(BATCH, DIM / 256, RCHUNKS), 256, 0, stream>>>(v, part);
    // 2) finalize mean
    colsum_final_kernel<<<dim3(BATCH, DIM / 256), 256, 0, stream>>>(part, vmean);
    // 3) t = vmean @ Wv.T + bv
    matvec_bt_kernel<<<dim3(BATCH, DIM / 4), 256, 0, stream>>>(vmean, Wv, bv, t);
    // 4) r = t @ Wo.T + bo
    matvec_bt_kernel<<<dim3(BATCH, DIM / 4), 256, 0, stream>>>(t, Wo, bo, r);
    // 5) broadcast to output
    bcast_kernel<<<2048, 256, 0, stream>>>(r, (float4*)out);
}